// Round 13
// baseline (174.102 us; speedup 1.0000x reference)
//
#include <hip/hip_runtime.h>
#include <hip/hip_bf16.h>

#define T_TOK 4096
#define H_DIM 768
#define E_NUM 8
#define F_DIM 1536

typedef __bf16 bf16x8 __attribute__((ext_vector_type(8)));
typedef unsigned short u16x8 __attribute__((ext_vector_type(8)));
typedef float f32x4 __attribute__((ext_vector_type(4)));
typedef unsigned int u32;

__device__ __forceinline__ unsigned short f2bf(float f) {
    unsigned int u = __float_as_uint(f);
    u += 0x7FFF + ((u >> 16) & 1);   // RNE
    return (unsigned short)(u >> 16);
}

__device__ __forceinline__ float bf2f(unsigned short s) {
    unsigned int u = ((unsigned int)s) << 16;
    return __uint_as_float(u);
}

// async global(16B/lane) -> LDS (wave-uniform base + lane*16)
__device__ __forceinline__ void gload16(const unsigned short* g, unsigned short* l) {
    __builtin_amdgcn_global_load_lds(
        (const __attribute__((address_space(1))) u32*)(g),
        (__attribute__((address_space(3))) u32*)(l),
        16, 0, 0);
}

// ---------------- router: logits + top2 + x->bf16, NO atomics ----------------
__global__ __launch_bounds__(256) void router_kernel(
    const float* __restrict__ x,
    const float* __restrict__ gw,
    float* __restrict__ logits_out,
    float* __restrict__ weight,
    int* __restrict__ eidx,
    unsigned short* __restrict__ xb) {
    int t = blockIdx.x * 4 + (threadIdx.x >> 6);
    int lane = threadIdx.x & 63;

    const float4* xr = reinterpret_cast<const float4*>(x + (size_t)t * H_DIM);
    float4 xv[3];
#pragma unroll
    for (int i = 0; i < 3; ++i) xv[i] = xr[i * 64 + lane];

    unsigned short* xbr = xb + (size_t)t * H_DIM;
#pragma unroll
    for (int i = 0; i < 3; ++i) {
        ushort4 o;
        o.x = f2bf(xv[i].x); o.y = f2bf(xv[i].y);
        o.z = f2bf(xv[i].z); o.w = f2bf(xv[i].w);
        *reinterpret_cast<ushort4*>(xbr + (i * 64 + lane) * 4) = o;
    }

    float v[E_NUM];
#pragma unroll
    for (int e = 0; e < E_NUM; ++e) {
        const float4* g = reinterpret_cast<const float4*>(gw + e * H_DIM);
        float p = 0.f;
#pragma unroll
        for (int i = 0; i < 3; ++i) {
            float4 gv = g[i * 64 + lane];
            p += xv[i].x * gv.x + xv[i].y * gv.y + xv[i].z * gv.z + xv[i].w * gv.w;
        }
        v[e] = p;
    }
#pragma unroll
    for (int d = 1; d < 8; d <<= 1)
#pragma unroll
        for (int e = 0; e < E_NUM; ++e) v[e] += __shfl_xor(v[e], d);
    int me = lane & 7;
    float le = v[0];
#pragma unroll
    for (int e = 1; e < E_NUM; ++e) le = (me == e) ? v[e] : le;
#pragma unroll
    for (int d = 8; d < 64; d <<= 1) le += __shfl_xor(le, d);

    if (lane < 8) logits_out[t * E_NUM + lane] = le;

    float m0 = le;
#pragma unroll
    for (int d = 1; d < 8; d <<= 1) m0 = fmaxf(m0, __shfl_xor(m0, d));
    unsigned long long b0 = __ballot(le == m0);
    int e0 = (__ffsll((long long)b0) - 1) & 7;
    float le1 = (me == e0) ? -3.4e38f : le;
    float m1 = le1;
#pragma unroll
    for (int d = 1; d < 8; d <<= 1) m1 = fmaxf(m1, __shfl_xor(m1, d));
    unsigned long long b1 = __ballot(le1 == m1);
    int e1 = (__ffsll((long long)b1) - 1) & 7;

    if (lane == 0) {
        float w0 = 1.f / (1.f + __expf(m1 - m0));
        weight[t * 2 + 0] = w0;
        weight[t * 2 + 1] = 1.f - w0;
        eidx[t] = e0 | (e1 << 8);
    }
}

// ---------------- build per-expert token lists (sorted, deterministic) ----------------
__global__ __launch_bounds__(256) void build_lists_kernel(
    const int* __restrict__ eidx,
    int* __restrict__ list,
    int* __restrict__ counts) {
    int e = blockIdx.x;
    int tid = threadIdx.x;
    int lane = tid & 63;
    int wv = tid >> 6;
    __shared__ int wsum[4];
    __shared__ int wbase[4];
    __shared__ int sbase;
    if (tid == 0) sbase = 0;
    __syncthreads();
    for (int c = 0; c < T_TOK; c += 256) {
        int tok = c + tid;
        int pk = eidx[tok];
        int slot = -1;
        if ((pk & 255) == e) slot = tok * 2;
        else if ((pk >> 8) == e) slot = tok * 2 + 1;
        unsigned long long m = __ballot(slot >= 0);
        int prefix = __popcll(m & ((1ull << lane) - 1ull));
        if (lane == 0) wsum[wv] = __popcll(m);
        __syncthreads();
        if (tid == 0) {
            int s = sbase;
#pragma unroll
            for (int i = 0; i < 4; ++i) { wbase[i] = s; s += wsum[i]; }
            sbase = s;
        }
        __syncthreads();
        if (slot >= 0) list[e * T_TOK + wbase[wv] + prefix] = slot;
        __syncthreads();
    }
    if (tid == 0) counts[e] = sbase;
}

// ---------------- GEMM 1&3 fused: act = silu(X w1^T) * (X w3^T) ----------------
// BM=128, BN=64, BK=32. A: gload_lds from bf16 xb. B: fp32 weights reg-staged
// (load early -> MFMA -> cvt+ds_write late). 2 buffers, 1 barrier/step.
__global__ __launch_bounds__(256, 3) void gemm13_kernel(
    const unsigned short* __restrict__ xb,
    const float* __restrict__ w1,
    const float* __restrict__ w3,
    const int* __restrict__ list,
    const int* __restrict__ counts,
    unsigned short* __restrict__ act) {
    int orig = blockIdx.x;
    int wg = (orig & 7) * 768 + (orig >> 3);
    int tm = wg & 31;
    int tn = (wg >> 5) % 24;
    int e = wg / (32 * 24);

    int cnt = counts[e];
    if (tm * 128 >= cnt) return;
    const int* lst = list + e * T_TOK + tm * 128;
    int mrem = cnt - tm * 128;

    __shared__ unsigned short sA[2][128 * 32];   // 16 KB
    __shared__ unsigned short sB1[2][64 * 32];   // 8 KB
    __shared__ unsigned short sB3[2][64 * 32];   // 8 KB

    int tid = threadIdx.x;
    int lane = tid & 63;
    int wid = tid >> 6;

    int r0 = tid >> 2;
    int r1 = r0 + 64;
    int c8 = ((tid & 3) ^ ((r0 >> 1) & 3)) * 8;   // pre-swizzled source chunk (elements)
    int ldsOff = r0 * 32 + (tid & 3) * 8;         // linear LDS slot (ushorts)
    int tok0 = lst[(r0 < mrem) ? r0 : 0] >> 1;
    int tok1 = lst[(r1 < mrem) ? r1 : 0] >> 1;
    const unsigned short* gA0 = xb + (size_t)tok0 * H_DIM + c8;
    const unsigned short* gA1 = xb + (size_t)tok1 * H_DIM + c8;
    const float* gw1 = w1 + ((size_t)e * F_DIM + tn * 64 + r0) * H_DIM + c8;
    const float* gw3 = w3 + ((size_t)e * F_DIM + tn * 64 + r0) * H_DIM + c8;

    auto writeB = [&](int b, float4 x1a, float4 x1b, float4 x3a, float4 x3b) {
        u16x8 o1, o3;
        o1[0] = f2bf(x1a.x); o1[1] = f2bf(x1a.y); o1[2] = f2bf(x1a.z); o1[3] = f2bf(x1a.w);
        o1[4] = f2bf(x1b.x); o1[5] = f2bf(x1b.y); o1[6] = f2bf(x1b.z); o1[7] = f2bf(x1b.w);
        o3[0] = f2bf(x3a.x); o3[1] = f2bf(x3a.y); o3[2] = f2bf(x3a.z); o3[3] = f2bf(x3a.w);
        o3[4] = f2bf(x3b.x); o3[5] = f2bf(x3b.y); o3[6] = f2bf(x3b.z); o3[7] = f2bf(x3b.w);
        *reinterpret_cast<u16x8*>(&sB1[b][ldsOff]) = o1;
        *reinterpret_cast<u16x8*>(&sB3[b][ldsOff]) = o3;
    };

    int wr = (wid >> 1) * 64;
    int wc = (wid & 1) * 32;
    int fr = lane & 15;
    int kb = ((lane >> 4) ^ ((lane >> 1) & 3)) * 8;  // read XOR (matches source pre-swizzle)

    f32x4 accG[4][2] = {};
    f32x4 accU[4][2] = {};

    const int NT = H_DIM / 32;   // 24

    // prologue: tile 0
    {
        float4 p1a = *reinterpret_cast<const float4*>(gw1);
        float4 p1b = *reinterpret_cast<const float4*>(gw1 + 4);
        float4 p3a = *reinterpret_cast<const float4*>(gw3);
        float4 p3b = *reinterpret_cast<const float4*>(gw3 + 4);
        gload16(gA0, &sA[0][wid * 512]);
        gload16(gA1, &sA[0][2048 + wid * 512]);
        writeB(0, p1a, p1b, p3a, p3b);
    }
    __syncthreads();

    int cur = 0;
    for (int t = 0; t < NT; ++t) {
        float4 n1a, n1b, n3a, n3b;
        bool pre = (t + 1 < NT);
        if (pre) {
            int kt = (t + 1) * 32;
            n1a = *reinterpret_cast<const float4*>(gw1 + kt);
            n1b = *reinterpret_cast<const float4*>(gw1 + kt + 4);
            n3a = *reinterpret_cast<const float4*>(gw3 + kt);
            n3b = *reinterpret_cast<const float4*>(gw3 + kt + 4);
            gload16(gA0 + kt, &sA[cur ^ 1][wid * 512]);
            gload16(gA1 + kt, &sA[cur ^ 1][2048 + wid * 512]);
        }

        bf16x8 a[4], b1[2], b3[2];
#pragma unroll
        for (int mi = 0; mi < 4; ++mi)
            a[mi] = *reinterpret_cast<const bf16x8*>(&sA[cur][(wr + mi * 16 + fr) * 32 + kb]);
#pragma unroll
        for (int ni = 0; ni < 2; ++ni) {
            b1[ni] = *reinterpret_cast<const bf16x8*>(&sB1[cur][(wc + ni * 16 + fr) * 32 + kb]);
            b3[ni] = *reinterpret_cast<const bf16x8*>(&sB3[cur][(wc + ni * 16 + fr) * 32 + kb]);
        }
#pragma unroll
        for (int mi = 0; mi < 4; ++mi)
#pragma unroll
            for (int ni = 0; ni < 2; ++ni) {
                accG[mi][ni] = __builtin_amdgcn_mfma_f32_16x16x32_bf16(a[mi], b1[ni], accG[mi][ni], 0, 0, 0);
                accU[mi][ni] = __builtin_amdgcn_mfma_f32_16x16x32_bf16(a[mi], b3[ni], accU[mi][ni], 0, 0, 0);
            }

        if (pre) writeB(cur ^ 1, n1a, n1b, n3a, n3b);
        __syncthreads();
        cur ^= 1;
    }

    int rg = (lane >> 4) * 4;
    int ci = lane & 15;
#pragma unroll
    for (int mi = 0; mi < 4; ++mi) {
#pragma unroll
        for (int r = 0; r < 4; ++r) {
            int m = wr + mi * 16 + rg + r;
            if (m >= mrem) continue;
            int entry = lst[m];
            size_t rowOff = (size_t)entry * F_DIM + tn * 64;
#pragma unroll
            for (int ni = 0; ni < 2; ++ni) {
                float g = accG[mi][ni][r];
                float u = accU[mi][ni][r];
                float s = g / (1.f + __expf(-g));
                act[rowOff + wc + ni * 16 + ci] = f2bf(s * u);
            }
        }
    }
}

// ---------------- GEMM 2: ybuf(bf16) = (act w2^T) * route_weight ----------------
// BM=128, BN=128, BK=32. A: gload_lds from bf16 act. B: fp32 w2 reg-staged.
__global__ __launch_bounds__(256, 3) void gemm2_kernel(
    const unsigned short* __restrict__ act,
    const float* __restrict__ w2,
    const int* __restrict__ list,
    const int* __restrict__ counts,
    const float* __restrict__ weight,
    unsigned short* __restrict__ ybuf) {
    int orig = blockIdx.x;
    int wg = (orig & 7) * 192 + (orig >> 3);
    int tm = wg & 31;
    int tn = (wg >> 5) % 6;
    int e = wg / (32 * 6);

    int cnt = counts[e];
    if (tm * 128 >= cnt) return;
    const int* lst = list + e * T_TOK + tm * 128;
    int mrem = cnt - tm * 128;

    __shared__ unsigned short sA[2][128 * 32];   // 16 KB
    __shared__ unsigned short sB[2][128 * 32];   // 16 KB

    int tid = threadIdx.x;
    int lane = tid & 63;
    int wid = tid >> 6;

    int r0 = tid >> 2;
    int r1 = r0 + 64;
    int c8 = ((tid & 3) ^ ((r0 >> 1) & 3)) * 8;
    int ldsOff = r0 * 32 + (tid & 3) * 8;
    int row0 = lst[(r0 < mrem) ? r0 : 0];
    int row1 = lst[(r1 < mrem) ? r1 : 0];
    const unsigned short* gA0 = act + (size_t)row0 * F_DIM + c8;
    const unsigned short* gA1 = act + (size_t)row1 * F_DIM + c8;
    const float* gw2a = w2 + ((size_t)e * H_DIM + tn * 128 + r0) * F_DIM + c8;
    const float* gw2b = gw2a + (size_t)64 * F_DIM;

    auto writeB = [&](int b, float4 xa0, float4 xa1, float4 xb0, float4 xb1) {
        u16x8 oa, ob;
        oa[0] = f2bf(xa0.x); oa[1] = f2bf(xa0.y); oa[2] = f2bf(xa0.z); oa[3] = f2bf(xa0.w);
        oa[4] = f2bf(xa1.x); oa[5] = f2bf(xa1.y); oa[6] = f2bf(xa1.z); oa[7] = f2bf(xa1.w);
        ob[0] = f2bf(xb0.x); ob[1] = f2bf(xb0.y); ob[2] = f2bf(xb0.z); ob[3] = f2bf(xb0.w);
        ob[4] = f2bf(xb1.x); ob[5] = f2bf(xb1.y); ob[6] = f2bf(xb1.z); ob[7] = f2bf(xb1.w);
        *reinterpret_cast<u16x8*>(&sB[b][ldsOff]) = oa;
        *reinterpret_cast<u16x8*>(&sB[b][2048 + ldsOff]) = ob;
    };

    int wr = (wid >> 1) * 64;
    int wc = (wid & 1) * 64;
    int fr = lane & 15;
    int kb = ((lane >> 4) ^ ((lane >> 1) & 3)) * 8;

    f32x4 acc[4][4] = {};

    const int NT = F_DIM / 32;   // 48

    {
        float4 pa0 = *reinterpret_cast<const float4*>(gw2a);
        float4 pa1 = *reinterpret_cast<const float4*>(gw2a + 4);
        float4 pb0 = *reinterpret_cast<const float4*>(gw2b);
        float4 pb1 = *reinterpret_cast<const float4*>(gw2b + 4);
        gload16(gA0, &sA[0][wid * 512]);
        gload16(gA1, &sA[0][2048 + wid * 512]);
        writeB(0, pa0, pa1, pb0, pb1);
    }
    __syncthreads();

    int cur = 0;
    for (int t = 0; t < NT; ++t) {
        float4 na0, na1, nb0, nb1;
        bool pre = (t + 1 < NT);
        if (pre) {
            int kt = (t + 1) * 32;
            na0 = *reinterpret_cast<const float4*>(gw2a + kt);
            na1 = *reinterpret_cast<const float4*>(gw2a + kt + 4);
            nb0 = *reinterpret_cast<const float4*>(gw2b + kt);
            nb1 = *reinterpret_cast<const float4*>(gw2b + kt + 4);
            gload16(gA0 + kt, &sA[cur ^ 1][wid * 512]);
            gload16(gA1 + kt, &sA[cur ^ 1][2048 + wid * 512]);
        }

        bf16x8 a[4], b[4];
#pragma unroll
        for (int mi = 0; mi < 4; ++mi)
            a[mi] = *reinterpret_cast<const bf16x8*>(&sA[cur][(wr + mi * 16 + fr) * 32 + kb]);
#pragma unroll
        for (int ni = 0; ni < 4; ++ni)
            b[ni] = *reinterpret_cast<const bf16x8*>(&sB[cur][(wc + ni * 16 + fr) * 32 + kb]);
#pragma unroll
        for (int mi = 0; mi < 4; ++mi)
#pragma unroll
            for (int ni = 0; ni < 4; ++ni)
                acc[mi][ni] = __builtin_amdgcn_mfma_f32_16x16x32_bf16(a[mi], b[ni], acc[mi][ni], 0, 0, 0);

        if (pre) writeB(cur ^ 1, na0, na1, nb0, nb1);
        __syncthreads();
        cur ^= 1;
    }

    int rg = (lane >> 4) * 4;
    int ci = lane & 15;
#pragma unroll
    for (int mi = 0; mi < 4; ++mi) {
#pragma unroll
        for (int r = 0; r < 4; ++r) {
            int m = wr + mi * 16 + rg + r;
            if (m >= mrem) continue;
            int entry = lst[m];
            float wv = weight[entry];
            size_t rowOff = (size_t)entry * H_DIM + tn * 128;
#pragma unroll
            for (int ni = 0; ni < 4; ++ni)
                ybuf[rowOff + wc + ni * 16 + ci] = f2bf(acc[mi][ni][r] * wv);
        }
    }
}

// ---------------- combine: y[t] = ybuf[2t] + ybuf[2t+1]  (bf16 in, fp32 out) ----------------
__global__ __launch_bounds__(256) void combine_kernel(
    const unsigned short* __restrict__ ybuf, float* __restrict__ y) {
    int v = blockIdx.x * blockDim.x + threadIdx.x;   // over T*H/8
    if (v >= T_TOK * H_DIM / 8) return;
    int t = v / (H_DIM / 8);
    int hv = (v % (H_DIM / 8)) * 8;
    const ushort4* pa = reinterpret_cast<const ushort4*>(ybuf + (size_t)(2 * t) * H_DIM + hv);
    const ushort4* pb = reinterpret_cast<const ushort4*>(ybuf + (size_t)(2 * t + 1) * H_DIM + hv);
    float* yo = y + (size_t)t * H_DIM + hv;
#pragma unroll
    for (int h = 0; h < 2; ++h) {
        ushort4 a = pa[h];
        ushort4 b = pb[h];
        float4 r;
        r.x = bf2f(a.x) + bf2f(b.x);
        r.y = bf2f(a.y) + bf2f(b.y);
        r.z = bf2f(a.z) + bf2f(b.z);
        r.w = bf2f(a.w) + bf2f(b.w);
        *reinterpret_cast<float4*>(yo + h * 4) = r;
    }
}

extern "C" void kernel_launch(void* const* d_in, const int* in_sizes, int n_in,
                              void* d_out, int out_size, void* d_ws, size_t ws_size,
                              hipStream_t stream) {
    const float* x  = (const float*)d_in[0];
    const float* gw = (const float*)d_in[1];
    const float* w1 = (const float*)d_in[2];
    const float* w3 = (const float*)d_in[3];
    const float* w2 = (const float*)d_in[4];

    float* y = (float*)d_out;
    float* logits_out = y + (size_t)T_TOK * H_DIM;

    char* ws = (char*)d_ws;
    size_t off = 0;
    auto alloc = [&](size_t bytes) -> char* {
        char* p = ws + off;
        off += (bytes + 255) & ~(size_t)255;
        return p;
    };
    unsigned short* xb   = (unsigned short*)alloc((size_t)T_TOK * H_DIM * 2);
    unsigned short* act  = (unsigned short*)alloc((size_t)T_TOK * 2 * F_DIM * 2);
    unsigned short* ybuf = (unsigned short*)alloc((size_t)T_TOK * 2 * H_DIM * 2);
    float* weight = (float*)alloc((size_t)T_TOK * 2 * 4);
    int* list     = (int*)alloc((size_t)E_NUM * T_TOK * 4);
    int* counts   = (int*)alloc((size_t)E_NUM * 4);
    int* eidx     = (int*)alloc((size_t)T_TOK * 4);

    router_kernel<<<T_TOK / 4, 256, 0, stream>>>(x, gw, logits_out, weight, eidx, xb);

    build_lists_kernel<<<E_NUM, 256, 0, stream>>>(eidx, list, counts);

    gemm13_kernel<<<6144, 256, 0, stream>>>(xb, w1, w3, list, counts, act);

    gemm2_kernel<<<1536, 256, 0, stream>>>(act, w2, list, counts, weight, ybuf);

    combine_kernel<<<(T_TOK * H_DIM / 8 + 255) / 256, 256, 0, stream>>>(ybuf, y);
}

// Round 14
// 162.844 us; speedup vs baseline: 1.0691x; 1.0691x over previous
//
#include <hip/hip_runtime.h>
#include <hip/hip_bf16.h>

#define T_TOK 4096
#define H_DIM 768
#define E_NUM 8
#define F_DIM 1536

typedef __bf16 bf16x8 __attribute__((ext_vector_type(8)));
typedef unsigned short u16x8 __attribute__((ext_vector_type(8)));
typedef float f32x4 __attribute__((ext_vector_type(4)));
typedef unsigned int u32;

#define WAITV6 asm volatile("s_waitcnt vmcnt(6) lgkmcnt(0)" ::: "memory")
#define WAITV0 asm volatile("s_waitcnt vmcnt(0) lgkmcnt(0)" ::: "memory")
#define CFENCE() asm volatile("" ::: "memory")

__device__ __forceinline__ unsigned short f2bf(float f) {
    unsigned int u = __float_as_uint(f);
    u += 0x7FFF + ((u >> 16) & 1);   // RNE
    return (unsigned short)(u >> 16);
}

__device__ __forceinline__ float bf2f(unsigned short s) {
    unsigned int u = ((unsigned int)s) << 16;
    return __uint_as_float(u);
}

// async global(16B/lane) -> LDS (wave-uniform base + lane*16)
__device__ __forceinline__ void gload16(const unsigned short* g, unsigned short* l) {
    __builtin_amdgcn_global_load_lds(
        (const __attribute__((address_space(1))) u32*)(g),
        (__attribute__((address_space(3))) u32*)(l),
        16, 0, 0);
}

// ---------------- router: logits + top2 + x->bf16, NO atomics ----------------
__global__ __launch_bounds__(256) void router_kernel(
    const float* __restrict__ x,
    const float* __restrict__ gw,
    float* __restrict__ logits_out,
    float* __restrict__ weight,
    int* __restrict__ eidx,
    unsigned short* __restrict__ xb) {
    int t = blockIdx.x * 4 + (threadIdx.x >> 6);
    int lane = threadIdx.x & 63;

    const float4* xr = reinterpret_cast<const float4*>(x + (size_t)t * H_DIM);
    float4 xv[3];
#pragma unroll
    for (int i = 0; i < 3; ++i) xv[i] = xr[i * 64 + lane];

    unsigned short* xbr = xb + (size_t)t * H_DIM;
#pragma unroll
    for (int i = 0; i < 3; ++i) {
        ushort4 o;
        o.x = f2bf(xv[i].x); o.y = f2bf(xv[i].y);
        o.z = f2bf(xv[i].z); o.w = f2bf(xv[i].w);
        *reinterpret_cast<ushort4*>(xbr + (i * 64 + lane) * 4) = o;
    }

    float v[E_NUM];
#pragma unroll
    for (int e = 0; e < E_NUM; ++e) {
        const float4* g = reinterpret_cast<const float4*>(gw + e * H_DIM);
        float p = 0.f;
#pragma unroll
        for (int i = 0; i < 3; ++i) {
            float4 gv = g[i * 64 + lane];
            p += xv[i].x * gv.x + xv[i].y * gv.y + xv[i].z * gv.z + xv[i].w * gv.w;
        }
        v[e] = p;
    }
#pragma unroll
    for (int d = 1; d < 8; d <<= 1)
#pragma unroll
        for (int e = 0; e < E_NUM; ++e) v[e] += __shfl_xor(v[e], d);
    int me = lane & 7;
    float le = v[0];
#pragma unroll
    for (int e = 1; e < E_NUM; ++e) le = (me == e) ? v[e] : le;
#pragma unroll
    for (int d = 8; d < 64; d <<= 1) le += __shfl_xor(le, d);

    if (lane < 8) logits_out[t * E_NUM + lane] = le;

    float m0 = le;
#pragma unroll
    for (int d = 1; d < 8; d <<= 1) m0 = fmaxf(m0, __shfl_xor(m0, d));
    unsigned long long b0 = __ballot(le == m0);
    int e0 = (__ffsll((long long)b0) - 1) & 7;
    float le1 = (me == e0) ? -3.4e38f : le;
    float m1 = le1;
#pragma unroll
    for (int d = 1; d < 8; d <<= 1) m1 = fmaxf(m1, __shfl_xor(m1, d));
    unsigned long long b1 = __ballot(le1 == m1);
    int e1 = (__ffsll((long long)b1) - 1) & 7;

    if (lane == 0) {
        float w0 = 1.f / (1.f + __expf(m1 - m0));
        weight[t * 2 + 0] = w0;
        weight[t * 2 + 1] = 1.f - w0;
        eidx[t] = e0 | (e1 << 8);
    }
}

// ---------------- build per-expert token lists (sorted, deterministic) ----------------
__global__ __launch_bounds__(256) void build_lists_kernel(
    const int* __restrict__ eidx,
    int* __restrict__ list,
    int* __restrict__ counts) {
    int e = blockIdx.x;
    int tid = threadIdx.x;
    int lane = tid & 63;
    int wv = tid >> 6;
    __shared__ int wsum[4];
    __shared__ int wbase[4];
    __shared__ int sbase;
    if (tid == 0) sbase = 0;
    __syncthreads();
    for (int c = 0; c < T_TOK; c += 256) {
        int tok = c + tid;
        int pk = eidx[tok];
        int slot = -1;
        if ((pk & 255) == e) slot = tok * 2;
        else if ((pk >> 8) == e) slot = tok * 2 + 1;
        unsigned long long m = __ballot(slot >= 0);
        int prefix = __popcll(m & ((1ull << lane) - 1ull));
        if (lane == 0) wsum[wv] = __popcll(m);
        __syncthreads();
        if (tid == 0) {
            int s = sbase;
#pragma unroll
            for (int i = 0; i < 4; ++i) { wbase[i] = s; s += wsum[i]; }
            sbase = s;
        }
        __syncthreads();
        if (slot >= 0) list[e * T_TOK + wbase[wv] + prefix] = slot;
        __syncthreads();
    }
    if (tid == 0) counts[e] = sbase;
}

// ---------------- GEMM 1&3 fused: act = silu(X w1^T) * (X w3^T) ----------------
// BM=128, BN=64, BK=32. A: 3-ring gload_lds depth-2. B: fp32 reg-staged depth-2
// (load t+2 / write t+1), counted vmcnt(6), raw barriers.
__global__ __launch_bounds__(256, 3) void gemm13_kernel(
    const unsigned short* __restrict__ xb,
    const float* __restrict__ w1,
    const float* __restrict__ w3,
    const int* __restrict__ list,
    const int* __restrict__ counts,
    unsigned short* __restrict__ act) {
    int orig = blockIdx.x;
    int wg = (orig & 7) * 768 + (orig >> 3);
    int tm = wg & 31;
    int tn = (wg >> 5) % 24;
    int e = wg / (32 * 24);

    int cnt = counts[e];
    if (tm * 128 >= cnt) return;
    const int* lst = list + e * T_TOK + tm * 128;
    int mrem = cnt - tm * 128;

    __shared__ unsigned short sA[3][128 * 32];   // 24 KB
    __shared__ unsigned short sB1[3][64 * 32];   // 12 KB
    __shared__ unsigned short sB3[3][64 * 32];   // 12 KB

    int tid = threadIdx.x;
    int lane = tid & 63;
    int wid = tid >> 6;

    int r0 = tid >> 2;
    int r1 = r0 + 64;
    int c8 = ((tid & 3) ^ ((r0 >> 1) & 3)) * 8;   // pre-swizzled source chunk
    int ldsOff = r0 * 32 + (tid & 3) * 8;         // linear LDS slot
    int tok0 = lst[(r0 < mrem) ? r0 : 0] >> 1;
    int tok1 = lst[(r1 < mrem) ? r1 : 0] >> 1;
    const unsigned short* gA0 = xb + (size_t)tok0 * H_DIM + c8;
    const unsigned short* gA1 = xb + (size_t)tok1 * H_DIM + c8;
    const float* gw1 = w1 + ((size_t)e * F_DIM + tn * 64 + r0) * H_DIM + c8;
    const float* gw3 = w3 + ((size_t)e * F_DIM + tn * 64 + r0) * H_DIM + c8;

    auto stageA = [&](int b, int kt) {
        gload16(gA0 + kt, &sA[b][wid * 512]);
        gload16(gA1 + kt, &sA[b][2048 + wid * 512]);
    };
    auto loadB = [&](float4 (&p)[4], int kt) {
        p[0] = *reinterpret_cast<const float4*>(gw1 + kt);
        p[1] = *reinterpret_cast<const float4*>(gw1 + kt + 4);
        p[2] = *reinterpret_cast<const float4*>(gw3 + kt);
        p[3] = *reinterpret_cast<const float4*>(gw3 + kt + 4);
    };
    auto writeB = [&](int b, const float4 (&p)[4]) {
        u16x8 o1, o3;
        o1[0] = f2bf(p[0].x); o1[1] = f2bf(p[0].y); o1[2] = f2bf(p[0].z); o1[3] = f2bf(p[0].w);
        o1[4] = f2bf(p[1].x); o1[5] = f2bf(p[1].y); o1[6] = f2bf(p[1].z); o1[7] = f2bf(p[1].w);
        o3[0] = f2bf(p[2].x); o3[1] = f2bf(p[2].y); o3[2] = f2bf(p[2].z); o3[3] = f2bf(p[2].w);
        o3[4] = f2bf(p[3].x); o3[5] = f2bf(p[3].y); o3[6] = f2bf(p[3].z); o3[7] = f2bf(p[3].w);
        *reinterpret_cast<u16x8*>(&sB1[b][ldsOff]) = o1;
        *reinterpret_cast<u16x8*>(&sB3[b][ldsOff]) = o3;
    };

    int wr = (wid >> 1) * 64;
    int wc = (wid & 1) * 32;
    int fr = lane & 15;
    int kb = ((lane >> 4) ^ ((lane >> 1) & 3)) * 8;

    f32x4 accG[4][2] = {};
    f32x4 accU[4][2] = {};

    const int NT = H_DIM / 32;   // 24 (even)

    float4 pS0[4], pS1[4];
    // prologue: tiles 0,1 in flight; B(0) written
    stageA(0, 0);  loadB(pS0, 0);
    stageA(1, 32); loadB(pS1, 32);
    writeB(0, pS0);
    __syncthreads();   // full drain once

    auto doStep = [&](int t, float4 (&ld)[4], float4 (&wr_)[4]) {
        if (t + 2 < NT) {
            stageA((t + 2) % 3, (t + 2) * 32);
            loadB(ld, (t + 2) * 32);
        }
        CFENCE();
        int cur = t % 3;
        bf16x8 a[4], b1[2], b3[2];
#pragma unroll
        for (int mi = 0; mi < 4; ++mi)
            a[mi] = *reinterpret_cast<const bf16x8*>(&sA[cur][(wr + mi * 16 + fr) * 32 + kb]);
#pragma unroll
        for (int ni = 0; ni < 2; ++ni) {
            b1[ni] = *reinterpret_cast<const bf16x8*>(&sB1[cur][(wc + ni * 16 + fr) * 32 + kb]);
            b3[ni] = *reinterpret_cast<const bf16x8*>(&sB3[cur][(wc + ni * 16 + fr) * 32 + kb]);
        }
#pragma unroll
        for (int mi = 0; mi < 4; ++mi)
#pragma unroll
            for (int ni = 0; ni < 2; ++ni) {
                accG[mi][ni] = __builtin_amdgcn_mfma_f32_16x16x32_bf16(a[mi], b1[ni], accG[mi][ni], 0, 0, 0);
                accU[mi][ni] = __builtin_amdgcn_mfma_f32_16x16x32_bf16(a[mi], b3[ni], accU[mi][ni], 0, 0, 0);
            }
        CFENCE();
        if (t + 1 < NT) {
            writeB((t + 1) % 3, wr_);
            if (t + 2 < NT) { WAITV6; } else { WAITV0; }
            __builtin_amdgcn_s_barrier();
            CFENCE();
        }
    };

    for (int t = 0; t < NT; t += 2) {
        doStep(t, pS0, pS1);       // load tile t+2 -> pS0, write tile t+1 from pS1
        doStep(t + 1, pS1, pS0);   // load tile t+3 -> pS1, write tile t+2 from pS0
    }

    int rg = (lane >> 4) * 4;
    int ci = lane & 15;
#pragma unroll
    for (int mi = 0; mi < 4; ++mi) {
#pragma unroll
        for (int r = 0; r < 4; ++r) {
            int m = wr + mi * 16 + rg + r;
            if (m >= mrem) continue;
            int entry = lst[m];
            size_t rowOff = (size_t)entry * F_DIM + tn * 64;
#pragma unroll
            for (int ni = 0; ni < 2; ++ni) {
                float g = accG[mi][ni][r];
                float u = accU[mi][ni][r];
                float s = g / (1.f + __expf(-g));
                act[rowOff + wc + ni * 16 + ci] = f2bf(s * u);
            }
        }
    }
}

// ---------------- GEMM 2: ybuf(bf16) = (act w2^T) * route_weight ----------------
// BM=128, BN=128, BK=32. A: 3-ring gload_lds depth-2. B: fp32 w2 reg-staged depth-2.
__global__ __launch_bounds__(256, 3) void gemm2_kernel(
    const unsigned short* __restrict__ act,
    const float* __restrict__ w2,
    const int* __restrict__ list,
    const int* __restrict__ counts,
    const float* __restrict__ weight,
    unsigned short* __restrict__ ybuf) {
    int orig = blockIdx.x;
    int wg = (orig & 7) * 192 + (orig >> 3);
    int tm = wg & 31;
    int tn = (wg >> 5) % 6;
    int e = wg / (32 * 6);

    int cnt = counts[e];
    if (tm * 128 >= cnt) return;
    const int* lst = list + e * T_TOK + tm * 128;
    int mrem = cnt - tm * 128;

    __shared__ unsigned short sA[3][128 * 32];   // 24 KB
    __shared__ unsigned short sB[3][128 * 32];   // 24 KB

    int tid = threadIdx.x;
    int lane = tid & 63;
    int wid = tid >> 6;

    int r0 = tid >> 2;
    int r1 = r0 + 64;
    int c8 = ((tid & 3) ^ ((r0 >> 1) & 3)) * 8;
    int ldsOff = r0 * 32 + (tid & 3) * 8;
    int row0 = lst[(r0 < mrem) ? r0 : 0];
    int row1 = lst[(r1 < mrem) ? r1 : 0];
    const unsigned short* gA0 = act + (size_t)row0 * F_DIM + c8;
    const unsigned short* gA1 = act + (size_t)row1 * F_DIM + c8;
    const float* gw2a = w2 + ((size_t)e * H_DIM + tn * 128 + r0) * F_DIM + c8;
    const float* gw2b = gw2a + (size_t)64 * F_DIM;

    auto stageA = [&](int b, int kt) {
        gload16(gA0 + kt, &sA[b][wid * 512]);
        gload16(gA1 + kt, &sA[b][2048 + wid * 512]);
    };
    auto loadB = [&](float4 (&p)[4], int kt) {
        p[0] = *reinterpret_cast<const float4*>(gw2a + kt);
        p[1] = *reinterpret_cast<const float4*>(gw2a + kt + 4);
        p[2] = *reinterpret_cast<const float4*>(gw2b + kt);
        p[3] = *reinterpret_cast<const float4*>(gw2b + kt + 4);
    };
    auto writeB = [&](int b, const float4 (&p)[4]) {
        u16x8 oa, ob;
        oa[0] = f2bf(p[0].x); oa[1] = f2bf(p[0].y); oa[2] = f2bf(p[0].z); oa[3] = f2bf(p[0].w);
        oa[4] = f2bf(p[1].x); oa[5] = f2bf(p[1].y); oa[6] = f2bf(p[1].z); oa[7] = f2bf(p[1].w);
        ob[0] = f2bf(p[2].x); ob[1] = f2bf(p[2].y); ob[2] = f2bf(p[2].z); ob[3] = f2bf(p[2].w);
        ob[4] = f2bf(p[3].x); ob[5] = f2bf(p[3].y); ob[6] = f2bf(p[3].z); ob[7] = f2bf(p[3].w);
        *reinterpret_cast<u16x8*>(&sB[b][ldsOff]) = oa;
        *reinterpret_cast<u16x8*>(&sB[b][2048 + ldsOff]) = ob;
    };

    int wr = (wid >> 1) * 64;
    int wc = (wid & 1) * 64;
    int fr = lane & 15;
    int kb = ((lane >> 4) ^ ((lane >> 1) & 3)) * 8;

    f32x4 acc[4][4] = {};

    const int NT = F_DIM / 32;   // 48 (even)

    float4 pS0[4], pS1[4];
    stageA(0, 0);  loadB(pS0, 0);
    stageA(1, 32); loadB(pS1, 32);
    writeB(0, pS0);
    __syncthreads();

    auto doStep = [&](int t, float4 (&ld)[4], float4 (&wr_)[4]) {
        if (t + 2 < NT) {
            stageA((t + 2) % 3, (t + 2) * 32);
            loadB(ld, (t + 2) * 32);
        }
        CFENCE();
        int cur = t % 3;
        bf16x8 a[4], b[4];
#pragma unroll
        for (int mi = 0; mi < 4; ++mi)
            a[mi] = *reinterpret_cast<const bf16x8*>(&sA[cur][(wr + mi * 16 + fr) * 32 + kb]);
#pragma unroll
        for (int ni = 0; ni < 4; ++ni)
            b[ni] = *reinterpret_cast<const bf16x8*>(&sB[cur][(wc + ni * 16 + fr) * 32 + kb]);
#pragma unroll
        for (int mi = 0; mi < 4; ++mi)
#pragma unroll
            for (int ni = 0; ni < 4; ++ni)
                acc[mi][ni] = __builtin_amdgcn_mfma_f32_16x16x32_bf16(a[mi], b[ni], acc[mi][ni], 0, 0, 0);
        CFENCE();
        if (t + 1 < NT) {
            writeB((t + 1) % 3, wr_);
            if (t + 2 < NT) { WAITV6; } else { WAITV0; }
            __builtin_amdgcn_s_barrier();
            CFENCE();
        }
    };

    for (int t = 0; t < NT; t += 2) {
        doStep(t, pS0, pS1);
        doStep(t + 1, pS1, pS0);
    }

    int rg = (lane >> 4) * 4;
    int ci = lane & 15;
#pragma unroll
    for (int mi = 0; mi < 4; ++mi) {
#pragma unroll
        for (int r = 0; r < 4; ++r) {
            int m = wr + mi * 16 + rg + r;
            if (m >= mrem) continue;
            int entry = lst[m];
            float wv = weight[entry];
            size_t rowOff = (size_t)entry * H_DIM + tn * 128;
#pragma unroll
            for (int ni = 0; ni < 4; ++ni)
                ybuf[rowOff + wc + ni * 16 + ci] = f2bf(acc[mi][ni][r] * wv);
        }
    }
}

// ---------------- combine: y[t] = ybuf[2t] + ybuf[2t+1]  (bf16 in, fp32 out) ----------------
__global__ __launch_bounds__(256) void combine_kernel(
    const unsigned short* __restrict__ ybuf, float* __restrict__ y) {
    int v = blockIdx.x * blockDim.x + threadIdx.x;   // over T*H/8
    if (v >= T_TOK * H_DIM / 8) return;
    int t = v / (H_DIM / 8);
    int hv = (v % (H_DIM / 8)) * 8;
    const ushort4* pa = reinterpret_cast<const ushort4*>(ybuf + (size_t)(2 * t) * H_DIM + hv);
    const ushort4* pb = reinterpret_cast<const ushort4*>(ybuf + (size_t)(2 * t + 1) * H_DIM + hv);
    float* yo = y + (size_t)t * H_DIM + hv;
#pragma unroll
    for (int h = 0; h < 2; ++h) {
        ushort4 a = pa[h];
        ushort4 b = pb[h];
        float4 r;
        r.x = bf2f(a.x) + bf2f(b.x);
        r.y = bf2f(a.y) + bf2f(b.y);
        r.z = bf2f(a.z) + bf2f(b.z);
        r.w = bf2f(a.w) + bf2f(b.w);
        *reinterpret_cast<float4*>(yo + h * 4) = r;
    }
}

extern "C" void kernel_launch(void* const* d_in, const int* in_sizes, int n_in,
                              void* d_out, int out_size, void* d_ws, size_t ws_size,
                              hipStream_t stream) {
    const float* x  = (const float*)d_in[0];
    const float* gw = (const float*)d_in[1];
    const float* w1 = (const float*)d_in[2];
    const float* w3 = (const float*)d_in[3];
    const float* w2 = (const float*)d_in[4];

    float* y = (float*)d_out;
    float* logits_out = y + (size_t)T_TOK * H_DIM;

    char* ws = (char*)d_ws;
    size_t off = 0;
    auto alloc = [&](size_t bytes) -> char* {
        char* p = ws + off;
        off += (bytes + 255) & ~(size_t)255;
        return p;
    };
    unsigned short* xb   = (unsigned short*)alloc((size_t)T_TOK * H_DIM * 2);
    unsigned short* act  = (unsigned short*)alloc((size_t)T_TOK * 2 * F_DIM * 2);
    unsigned short* ybuf = (unsigned short*)alloc((size_t)T_TOK * 2 * H_DIM * 2);
    float* weight = (float*)alloc((size_t)T_TOK * 2 * 4);
    int* list     = (int*)alloc((size_t)E_NUM * T_TOK * 4);
    int* counts   = (int*)alloc((size_t)E_NUM * 4);
    int* eidx     = (int*)alloc((size_t)T_TOK * 4);

    router_kernel<<<T_TOK / 4, 256, 0, stream>>>(x, gw, logits_out, weight, eidx, xb);

    build_lists_kernel<<<E_NUM, 256, 0, stream>>>(eidx, list, counts);

    gemm13_kernel<<<6144, 256, 0, stream>>>(xb, w1, w3, list, counts, act);

    gemm2_kernel<<<1536, 256, 0, stream>>>(act, w2, list, counts, weight, ybuf);

    combine_kernel<<<(T_TOK * H_DIM / 8 + 255) / 256, 256, 0, stream>>>(ybuf, y);
}

// Round 15
// 153.016 us; speedup vs baseline: 1.1378x; 1.0642x over previous
//
#include <hip/hip_runtime.h>
#include <hip/hip_bf16.h>

#define T_TOK 4096
#define H_DIM 768
#define E_NUM 8
#define F_DIM 1536
#define WELEM (E_NUM * F_DIM * H_DIM)   // 9437184

typedef __bf16 bf16x8 __attribute__((ext_vector_type(8)));
typedef float f32x4 __attribute__((ext_vector_type(4)));
typedef unsigned int u32;

#define VMCNT(n) asm volatile("s_waitcnt vmcnt(" #n ")" ::: "memory")
#define CFENCE() asm volatile("" ::: "memory")

__device__ __forceinline__ unsigned short f2bf(float f) {
    unsigned int u = __float_as_uint(f);
    u += 0x7FFF + ((u >> 16) & 1);   // RNE
    return (unsigned short)(u >> 16);
}

__device__ __forceinline__ float bf2f(unsigned short s) {
    unsigned int u = ((unsigned int)s) << 16;
    return __uint_as_float(u);
}

// async global(16B/lane) -> LDS (wave-uniform base + lane*16)
__device__ __forceinline__ void gload16(const unsigned short* g, unsigned short* l) {
    __builtin_amdgcn_global_load_lds(
        (const __attribute__((address_space(1))) u32*)(g),
        (__attribute__((address_space(3))) u32*)(l),
        16, 0, 0);
}

// ---------------- prologue: router (blocks 0..1023) + w1/w3 converts (rest) ----------------
__global__ __launch_bounds__(256) void prologue_kernel(
    const float* __restrict__ x,
    const float* __restrict__ gw,
    const float* __restrict__ w1,
    const float* __restrict__ w3,
    float* __restrict__ logits_out,
    float* __restrict__ weight,
    int* __restrict__ eidx,
    unsigned short* __restrict__ xb,
    unsigned short* __restrict__ w1b,
    unsigned short* __restrict__ w3b) {
    int tid = threadIdx.x;
    if (blockIdx.x >= 1024) {
        int cb = blockIdx.x - 1024;
        int i = (cb * 256 + tid) * 4;
        int stride = (gridDim.x - 1024) * 256 * 4;
        for (; i < 2 * WELEM; i += stride) {
            int r = i / WELEM;
            int j = i - r * WELEM;
            const float* s = (r == 0) ? w1 : w3;
            unsigned short* d = (r == 0) ? w1b : w3b;
            float4 v = *reinterpret_cast<const float4*>(s + j);
            ushort4 o;
            o.x = f2bf(v.x); o.y = f2bf(v.y); o.z = f2bf(v.z); o.w = f2bf(v.w);
            *reinterpret_cast<ushort4*>(d + j) = o;
        }
        return;
    }
    // ---- router part: 1 wave per token ----
    int t = blockIdx.x * 4 + (tid >> 6);
    int lane = tid & 63;

    const float4* xr = reinterpret_cast<const float4*>(x + (size_t)t * H_DIM);
    float4 xv[3];
#pragma unroll
    for (int i = 0; i < 3; ++i) xv[i] = xr[i * 64 + lane];

    unsigned short* xbr = xb + (size_t)t * H_DIM;
#pragma unroll
    for (int i = 0; i < 3; ++i) {
        ushort4 o;
        o.x = f2bf(xv[i].x); o.y = f2bf(xv[i].y);
        o.z = f2bf(xv[i].z); o.w = f2bf(xv[i].w);
        *reinterpret_cast<ushort4*>(xbr + (i * 64 + lane) * 4) = o;
    }

    float v[E_NUM];
#pragma unroll
    for (int e = 0; e < E_NUM; ++e) {
        const float4* g = reinterpret_cast<const float4*>(gw + e * H_DIM);
        float p = 0.f;
#pragma unroll
        for (int i = 0; i < 3; ++i) {
            float4 gv = g[i * 64 + lane];
            p += xv[i].x * gv.x + xv[i].y * gv.y + xv[i].z * gv.z + xv[i].w * gv.w;
        }
        v[e] = p;
    }
#pragma unroll
    for (int d = 1; d < 8; d <<= 1)
#pragma unroll
        for (int e = 0; e < E_NUM; ++e) v[e] += __shfl_xor(v[e], d);
    int me = lane & 7;
    float le = v[0];
#pragma unroll
    for (int e = 1; e < E_NUM; ++e) le = (me == e) ? v[e] : le;
#pragma unroll
    for (int d = 8; d < 64; d <<= 1) le += __shfl_xor(le, d);

    if (lane < 8) logits_out[t * E_NUM + lane] = le;

    float m0 = le;
#pragma unroll
    for (int d = 1; d < 8; d <<= 1) m0 = fmaxf(m0, __shfl_xor(m0, d));
    unsigned long long b0 = __ballot(le == m0);
    int e0 = (__ffsll((long long)b0) - 1) & 7;
    float le1 = (me == e0) ? -3.4e38f : le;
    float m1 = le1;
#pragma unroll
    for (int d = 1; d < 8; d <<= 1) m1 = fmaxf(m1, __shfl_xor(m1, d));
    unsigned long long b1 = __ballot(le1 == m1);
    int e1 = (__ffsll((long long)b1) - 1) & 7;

    if (lane == 0) {
        float w0 = 1.f / (1.f + __expf(m1 - m0));
        weight[t * 2 + 0] = w0;
        weight[t * 2 + 1] = 1.f - w0;
        eidx[t] = e0 | (e1 << 8);
    }
}

// ---------------- build per-expert token lists (sorted, deterministic) ----------------
__global__ __launch_bounds__(256) void build_lists_kernel(
    const int* __restrict__ eidx,
    int* __restrict__ list,
    int* __restrict__ counts) {
    int e = blockIdx.x;
    int tid = threadIdx.x;
    int lane = tid & 63;
    int wv = tid >> 6;
    __shared__ int wsum[4];
    __shared__ int wbase[4];
    __shared__ int sbase;
    if (tid == 0) sbase = 0;
    __syncthreads();
    for (int c = 0; c < T_TOK; c += 256) {
        int tok = c + tid;
        int pk = eidx[tok];
        int slot = -1;
        if ((pk & 255) == e) slot = tok * 2;
        else if ((pk >> 8) == e) slot = tok * 2 + 1;
        unsigned long long m = __ballot(slot >= 0);
        int prefix = __popcll(m & ((1ull << lane) - 1ull));
        if (lane == 0) wsum[wv] = __popcll(m);
        __syncthreads();
        if (tid == 0) {
            int s = sbase;
#pragma unroll
            for (int i = 0; i < 4; ++i) { wbase[i] = s; s += wsum[i]; }
            sbase = s;
        }
        __syncthreads();
        if (slot >= 0) list[e * T_TOK + wbase[wv] + prefix] = slot;
        __syncthreads();
    }
    if (tid == 0) counts[e] = sbase;
}

// ---------------- GEMM 1&3 fused: act = silu(X w1^T) * (X w3^T) ----------------
// BM=128, BN=64, BK=32, 3-ring, depth-2, counted vmcnt (R8/R12 schedule).
// Inactive blocks convert w2 fp32->bf16 (deterministic rank-based partition).
__global__ __launch_bounds__(256, 3) void gemm13_kernel(
    const unsigned short* __restrict__ xb,
    const unsigned short* __restrict__ w1b,
    const unsigned short* __restrict__ w3b,
    const int* __restrict__ list,
    const int* __restrict__ counts,
    unsigned short* __restrict__ act,
    const float* __restrict__ w2,
    unsigned short* __restrict__ w2b) {
    int orig = blockIdx.x;
    int wg = (orig & 7) * 768 + (orig >> 3);
    int tm = wg & 31;
    int tn = (wg >> 5) % 24;
    int e = wg / (32 * 24);

    int cnt = counts[e];
    if (tm * 128 >= cnt) {
        // -------- inactive: help convert w2 --------
        int acts[E_NUM];
        int total = 0;
#pragma unroll
        for (int k = 0; k < E_NUM; ++k) {
            int a = (counts[k] + 127) >> 7;
            acts[k] = a;
            total += 24 * (32 - a);
        }
        int rank = 0;
#pragma unroll
        for (int k = 0; k < E_NUM; ++k) if (k < e) rank += 24 * (32 - acts[k]);
        rank += tn * (32 - acts[e]) + (tm - acts[e]);
        const int NCHUNK = WELEM / 4096;   // 2304
        for (int c = rank; c < NCHUNK; c += total) {
#pragma unroll
            for (int pass = 0; pass < 4; ++pass) {
                int idx = c * 4096 + pass * 1024 + threadIdx.x * 4;
                float4 v = *reinterpret_cast<const float4*>(w2 + idx);
                ushort4 o;
                o.x = f2bf(v.x); o.y = f2bf(v.y); o.z = f2bf(v.z); o.w = f2bf(v.w);
                *reinterpret_cast<ushort4*>(w2b + idx) = o;
            }
        }
        return;
    }
    const int* lst = list + e * T_TOK + tm * 128;
    int mrem = cnt - tm * 128;

    __shared__ unsigned short sA[3][128 * 32];   // 24 KB
    __shared__ unsigned short sB1[3][64 * 32];   // 12 KB
    __shared__ unsigned short sB3[3][64 * 32];   // 12 KB

    int tid = threadIdx.x;
    int lane = tid & 63;
    int wid = tid >> 6;

    int r0 = tid >> 2;
    int r1 = r0 + 64;
    int c8 = ((tid & 3) ^ ((r0 >> 1) & 3)) * 8;   // bank-correct pre-swizzle
    int tok0 = lst[(r0 < mrem) ? r0 : 0] >> 1;
    int tok1 = lst[(r1 < mrem) ? r1 : 0] >> 1;
    const unsigned short* gA0 = xb + (size_t)tok0 * H_DIM + c8;
    const unsigned short* gA1 = xb + (size_t)tok1 * H_DIM + c8;
    const unsigned short* gB1 = w1b + ((size_t)e * F_DIM + tn * 64 + r0) * H_DIM + c8;
    const unsigned short* gB3 = w3b + ((size_t)e * F_DIM + tn * 64 + r0) * H_DIM + c8;

    auto stage = [&](int b, int kt) {
        gload16(gA0 + kt, &sA[b][wid * 512]);
        gload16(gA1 + kt, &sA[b][2048 + wid * 512]);
        gload16(gB1 + kt, &sB1[b][wid * 512]);
        gload16(gB3 + kt, &sB3[b][wid * 512]);
    };

    int wr = (wid >> 1) * 64;
    int wc = (wid & 1) * 32;
    int fr = lane & 15;
    int kb = ((lane >> 4) ^ ((lane >> 1) & 3)) * 8;  // matching read XOR

    f32x4 accG[4][2] = {};
    f32x4 accU[4][2] = {};

    const int NT = H_DIM / 32;   // 24
    stage(0, 0);
    stage(1, 32);
    int cur = 0;
    for (int t = 0; t < NT; ++t) {
        if (t + 2 < NT) {
            int nb = cur + 2; if (nb >= 3) nb -= 3;
            stage(nb, (t + 2) * 32);
            VMCNT(8);
        } else if (t + 1 < NT) {
            VMCNT(4);
        } else {
            VMCNT(0);
        }
        __builtin_amdgcn_s_barrier();
        CFENCE();

        bf16x8 a[4], b1[2], b3[2];
#pragma unroll
        for (int mi = 0; mi < 4; ++mi)
            a[mi] = *reinterpret_cast<const bf16x8*>(&sA[cur][(wr + mi * 16 + fr) * 32 + kb]);
#pragma unroll
        for (int ni = 0; ni < 2; ++ni) {
            b1[ni] = *reinterpret_cast<const bf16x8*>(&sB1[cur][(wc + ni * 16 + fr) * 32 + kb]);
            b3[ni] = *reinterpret_cast<const bf16x8*>(&sB3[cur][(wc + ni * 16 + fr) * 32 + kb]);
        }
#pragma unroll
        for (int mi = 0; mi < 4; ++mi)
#pragma unroll
            for (int ni = 0; ni < 2; ++ni) {
                accG[mi][ni] = __builtin_amdgcn_mfma_f32_16x16x32_bf16(a[mi], b1[ni], accG[mi][ni], 0, 0, 0);
                accU[mi][ni] = __builtin_amdgcn_mfma_f32_16x16x32_bf16(a[mi], b3[ni], accU[mi][ni], 0, 0, 0);
            }
        CFENCE();
        __builtin_amdgcn_s_barrier();
        cur = (cur + 1 < 3) ? cur + 1 : 0;
    }

    int rg = (lane >> 4) * 4;
    int ci = lane & 15;
#pragma unroll
    for (int mi = 0; mi < 4; ++mi) {
#pragma unroll
        for (int r = 0; r < 4; ++r) {
            int m = wr + mi * 16 + rg + r;
            if (m >= mrem) continue;
            int entry = lst[m];
            size_t rowOff = (size_t)entry * F_DIM + tn * 64;
#pragma unroll
            for (int ni = 0; ni < 2; ++ni) {
                float g = accG[mi][ni][r];
                float u = accU[mi][ni][r];
                float s = g / (1.f + __expf(-g));
                act[rowOff + wc + ni * 16 + ci] = f2bf(s * u);
            }
        }
    }
}

// ---------------- GEMM 2: ybuf(bf16) = (act w2^T) * route_weight ----------------
// BM=128, BN=128, BK=32, 3-ring, depth 2, counted vmcnt (R8/R12 schedule).
__global__ __launch_bounds__(256, 3) void gemm2_kernel(
    const unsigned short* __restrict__ act,
    const unsigned short* __restrict__ w2b,
    const int* __restrict__ list,
    const int* __restrict__ counts,
    const float* __restrict__ weight,
    unsigned short* __restrict__ ybuf) {
    int orig = blockIdx.x;
    int wg = (orig & 7) * 192 + (orig >> 3);
    int tm = wg & 31;
    int tn = (wg >> 5) % 6;
    int e = wg / (32 * 6);

    int cnt = counts[e];
    if (tm * 128 >= cnt) return;
    const int* lst = list + e * T_TOK + tm * 128;
    int mrem = cnt - tm * 128;

    __shared__ unsigned short sA[3][128 * 32];   // 24 KB
    __shared__ unsigned short sB[3][128 * 32];   // 24 KB

    int tid = threadIdx.x;
    int lane = tid & 63;
    int wid = tid >> 6;

    int r0 = tid >> 2;
    int r1 = r0 + 64;
    int c8 = ((tid & 3) ^ ((r0 >> 1) & 3)) * 8;
    int row0 = lst[(r0 < mrem) ? r0 : 0];
    int row1 = lst[(r1 < mrem) ? r1 : 0];
    const unsigned short* gA0 = act + (size_t)row0 * F_DIM + c8;
    const unsigned short* gA1 = act + (size_t)row1 * F_DIM + c8;
    const unsigned short* gB0 = w2b + ((size_t)e * H_DIM + tn * 128 + r0) * F_DIM + c8;
    const unsigned short* gB1 = gB0 + (size_t)64 * F_DIM;

    auto stage = [&](int b, int kt) {
        gload16(gA0 + kt, &sA[b][wid * 512]);
        gload16(gA1 + kt, &sA[b][2048 + wid * 512]);
        gload16(gB0 + kt, &sB[b][wid * 512]);
        gload16(gB1 + kt, &sB[b][2048 + wid * 512]);
    };

    int wr = (wid >> 1) * 64;
    int wc = (wid & 1) * 64;
    int fr = lane & 15;
    int kb = ((lane >> 4) ^ ((lane >> 1) & 3)) * 8;

    f32x4 acc[4][4] = {};

    const int NT = F_DIM / 32;   // 48
    stage(0, 0);
    stage(1, 32);
    int cur = 0;
    for (int t = 0; t < NT; ++t) {
        if (t + 2 < NT) {
            int nb = cur + 2; if (nb >= 3) nb -= 3;
            stage(nb, (t + 2) * 32);
            VMCNT(8);
        } else if (t + 1 < NT) {
            VMCNT(4);
        } else {
            VMCNT(0);
        }
        __builtin_amdgcn_s_barrier();
        CFENCE();

        bf16x8 a[4], b[4];
#pragma unroll
        for (int mi = 0; mi < 4; ++mi)
            a[mi] = *reinterpret_cast<const bf16x8*>(&sA[cur][(wr + mi * 16 + fr) * 32 + kb]);
#pragma unroll
        for (int ni = 0; ni < 4; ++ni)
            b[ni] = *reinterpret_cast<const bf16x8*>(&sB[cur][(wc + ni * 16 + fr) * 32 + kb]);
#pragma unroll
        for (int mi = 0; mi < 4; ++mi)
#pragma unroll
            for (int ni = 0; ni < 4; ++ni)
                acc[mi][ni] = __builtin_amdgcn_mfma_f32_16x16x32_bf16(a[mi], b[ni], acc[mi][ni], 0, 0, 0);
        CFENCE();
        __builtin_amdgcn_s_barrier();
        cur = (cur + 1 < 3) ? cur + 1 : 0;
    }

    int rg = (lane >> 4) * 4;
    int ci = lane & 15;
#pragma unroll
    for (int mi = 0; mi < 4; ++mi) {
#pragma unroll
        for (int r = 0; r < 4; ++r) {
            int m = wr + mi * 16 + rg + r;
            if (m >= mrem) continue;
            int entry = lst[m];
            float wv = weight[entry];
            size_t rowOff = (size_t)entry * H_DIM + tn * 128;
#pragma unroll
            for (int ni = 0; ni < 4; ++ni)
                ybuf[rowOff + wc + ni * 16 + ci] = f2bf(acc[mi][ni][r] * wv);
        }
    }
}

// ---------------- combine: y[t] = ybuf[2t] + ybuf[2t+1]  (bf16 in, fp32 out) ----------------
__global__ __launch_bounds__(256) void combine_kernel(
    const unsigned short* __restrict__ ybuf, float* __restrict__ y) {
    int v = blockIdx.x * blockDim.x + threadIdx.x;   // over T*H/8
    if (v >= T_TOK * H_DIM / 8) return;
    int t = v / (H_DIM / 8);
    int hv = (v % (H_DIM / 8)) * 8;
    const ushort4* pa = reinterpret_cast<const ushort4*>(ybuf + (size_t)(2 * t) * H_DIM + hv);
    const ushort4* pb = reinterpret_cast<const ushort4*>(ybuf + (size_t)(2 * t + 1) * H_DIM + hv);
    float* yo = y + (size_t)t * H_DIM + hv;
#pragma unroll
    for (int h = 0; h < 2; ++h) {
        ushort4 a = pa[h];
        ushort4 b = pb[h];
        float4 r;
        r.x = bf2f(a.x) + bf2f(b.x);
        r.y = bf2f(a.y) + bf2f(b.y);
        r.z = bf2f(a.z) + bf2f(b.z);
        r.w = bf2f(a.w) + bf2f(b.w);
        *reinterpret_cast<float4*>(yo + h * 4) = r;
    }
}

extern "C" void kernel_launch(void* const* d_in, const int* in_sizes, int n_in,
                              void* d_out, int out_size, void* d_ws, size_t ws_size,
                              hipStream_t stream) {
    const float* x  = (const float*)d_in[0];
    const float* gw = (const float*)d_in[1];
    const float* w1 = (const float*)d_in[2];
    const float* w3 = (const float*)d_in[3];
    const float* w2 = (const float*)d_in[4];

    float* y = (float*)d_out;
    float* logits_out = y + (size_t)T_TOK * H_DIM;

    char* ws = (char*)d_ws;
    size_t off = 0;
    auto alloc = [&](size_t bytes) -> char* {
        char* p = ws + off;
        off += (bytes + 255) & ~(size_t)255;
        return p;
    };
    unsigned short* xb   = (unsigned short*)alloc((size_t)T_TOK * H_DIM * 2);
    unsigned short* w1b  = (unsigned short*)alloc((size_t)WELEM * 2);
    unsigned short* w3b  = (unsigned short*)alloc((size_t)WELEM * 2);
    unsigned short* w2b  = (unsigned short*)alloc((size_t)WELEM * 2);
    unsigned short* act  = (unsigned short*)alloc((size_t)T_TOK * 2 * F_DIM * 2);
    unsigned short* ybuf = (unsigned short*)alloc((size_t)T_TOK * 2 * H_DIM * 2);
    float* weight = (float*)alloc((size_t)T_TOK * 2 * 4);
    int* list     = (int*)alloc((size_t)E_NUM * T_TOK * 4);
    int* counts   = (int*)alloc((size_t)E_NUM * 4);
    int* eidx     = (int*)alloc((size_t)T_TOK * 4);

    prologue_kernel<<<3328, 256, 0, stream>>>(x, gw, w1, w3,
                                              logits_out, weight, eidx, xb,
                                              w1b, w3b);

    build_lists_kernel<<<E_NUM, 256, 0, stream>>>(eidx, list, counts);

    gemm13_kernel<<<6144, 256, 0, stream>>>(xb, w1b, w3b, list, counts, act, w2, w2b);

    gemm2_kernel<<<1536, 256, 0, stream>>>(act, w2b, list, counts, weight, ybuf);

    combine_kernel<<<(T_TOK * H_DIM / 8 + 255) / 256, 256, 0, stream>>>(ybuf, y);
}

// Round 16
// 148.236 us; speedup vs baseline: 1.1745x; 1.0322x over previous
//
#include <hip/hip_runtime.h>
#include <hip/hip_bf16.h>

#define T_TOK 4096
#define H_DIM 768
#define E_NUM 8
#define F_DIM 1536
#define WELEM (E_NUM * F_DIM * H_DIM)   // 9437184

typedef __bf16 bf16x8 __attribute__((ext_vector_type(8)));
typedef float f32x4 __attribute__((ext_vector_type(4)));
typedef unsigned int u32;

#define VMCNT(n) asm volatile("s_waitcnt vmcnt(" #n ")" ::: "memory")
#define CFENCE() asm volatile("" ::: "memory")

__device__ __forceinline__ unsigned short f2bf(float f) {
    unsigned int u = __float_as_uint(f);
    u += 0x7FFF + ((u >> 16) & 1);   // RNE
    return (unsigned short)(u >> 16);
}

__device__ __forceinline__ float bf2f(unsigned short s) {
    unsigned int u = ((unsigned int)s) << 16;
    return __uint_as_float(u);
}

// async global(16B/lane) -> LDS (wave-uniform base + lane*16)
__device__ __forceinline__ void gload16(const unsigned short* g, unsigned short* l) {
    __builtin_amdgcn_global_load_lds(
        (const __attribute__((address_space(1))) u32*)(g),
        (__attribute__((address_space(3))) u32*)(l),
        16, 0, 0);
}

// ---------------- prologue: router (blocks 0..1023) + w1/w3 converts ----------------
// Convert blocks: w1 -> [1024,2176), w3 -> [2176,3328). Exact-fit strides, no div.
__global__ __launch_bounds__(256) void prologue_kernel(
    const float* __restrict__ x,
    const float* __restrict__ gw,
    const float* __restrict__ w1,
    const float* __restrict__ w3,
    float* __restrict__ logits_out,
    float* __restrict__ weight,
    int* __restrict__ eidx,
    unsigned short* __restrict__ xb,
    unsigned short* __restrict__ w1b,
    unsigned short* __restrict__ w3b) {
    int tid = threadIdx.x;
    if (blockIdx.x >= 1024) {
        int r = (blockIdx.x >= 1024 + 1152) ? 1 : 0;
        int cb = blockIdx.x - 1024 - r * 1152;
        const float* s = r ? w3 : w1;
        unsigned short* d = r ? w3b : w1b;
        int base = (cb * 256 + tid) * 4;
        const int stride = 1152 * 256 * 4;   // 1179648; x8 = WELEM exactly
#pragma unroll
        for (int it = 0; it < 8; ++it) {
            int j = base + it * stride;
            float4 v = *reinterpret_cast<const float4*>(s + j);
            ushort4 o;
            o.x = f2bf(v.x); o.y = f2bf(v.y); o.z = f2bf(v.z); o.w = f2bf(v.w);
            *reinterpret_cast<ushort4*>(d + j) = o;
        }
        return;
    }
    // ---- router part: 1 wave per token ----
    int t = blockIdx.x * 4 + (tid >> 6);
    int lane = tid & 63;

    const float4* xr = reinterpret_cast<const float4*>(x + (size_t)t * H_DIM);
    float4 xv[3];
#pragma unroll
    for (int i = 0; i < 3; ++i) xv[i] = xr[i * 64 + lane];

    unsigned short* xbr = xb + (size_t)t * H_DIM;
#pragma unroll
    for (int i = 0; i < 3; ++i) {
        ushort4 o;
        o.x = f2bf(xv[i].x); o.y = f2bf(xv[i].y);
        o.z = f2bf(xv[i].z); o.w = f2bf(xv[i].w);
        *reinterpret_cast<ushort4*>(xbr + (i * 64 + lane) * 4) = o;
    }

    float v[E_NUM];
#pragma unroll
    for (int e = 0; e < E_NUM; ++e) {
        const float4* g = reinterpret_cast<const float4*>(gw + e * H_DIM);
        float p = 0.f;
#pragma unroll
        for (int i = 0; i < 3; ++i) {
            float4 gv = g[i * 64 + lane];
            p += xv[i].x * gv.x + xv[i].y * gv.y + xv[i].z * gv.z + xv[i].w * gv.w;
        }
        v[e] = p;
    }
#pragma unroll
    for (int d = 1; d < 8; d <<= 1)
#pragma unroll
        for (int e = 0; e < E_NUM; ++e) v[e] += __shfl_xor(v[e], d);
    int me = lane & 7;
    float le = v[0];
#pragma unroll
    for (int e = 1; e < E_NUM; ++e) le = (me == e) ? v[e] : le;
#pragma unroll
    for (int d = 8; d < 64; d <<= 1) le += __shfl_xor(le, d);

    if (lane < 8) logits_out[t * E_NUM + lane] = le;

    float m0 = le;
#pragma unroll
    for (int d = 1; d < 8; d <<= 1) m0 = fmaxf(m0, __shfl_xor(m0, d));
    unsigned long long b0 = __ballot(le == m0);
    int e0 = (__ffsll((long long)b0) - 1) & 7;
    float le1 = (me == e0) ? -3.4e38f : le;
    float m1 = le1;
#pragma unroll
    for (int d = 1; d < 8; d <<= 1) m1 = fmaxf(m1, __shfl_xor(m1, d));
    unsigned long long b1 = __ballot(le1 == m1);
    int e1 = (__ffsll((long long)b1) - 1) & 7;

    if (lane == 0) {
        float w0 = 1.f / (1.f + __expf(m1 - m0));
        weight[t * 2 + 0] = w0;
        weight[t * 2 + 1] = 1.f - w0;
        eidx[t] = e0 | (e1 << 8);
    }
}

// ---------------- build lists (blocks 0..7) + w2 convert (blocks 8..2311) ----------------
__global__ __launch_bounds__(256) void build_lists_kernel(
    const int* __restrict__ eidx,
    int* __restrict__ list,
    int* __restrict__ counts,
    const float* __restrict__ w2,
    unsigned short* __restrict__ w2b) {
    int tid = threadIdx.x;
    if (blockIdx.x >= 8) {
        int cb = blockIdx.x - 8;
        int base = (cb * 256 + tid) * 4;
        const int stride = 2304 * 256 * 4;   // 2359296; x4 = WELEM exactly
#pragma unroll
        for (int it = 0; it < 4; ++it) {
            int j = base + it * stride;
            float4 v = *reinterpret_cast<const float4*>(w2 + j);
            ushort4 o;
            o.x = f2bf(v.x); o.y = f2bf(v.y); o.z = f2bf(v.z); o.w = f2bf(v.w);
            *reinterpret_cast<ushort4*>(w2b + j) = o;
        }
        return;
    }
    int e = blockIdx.x;
    int lane = tid & 63;
    int wv = tid >> 6;
    __shared__ int wsum[4];
    __shared__ int wbase[4];
    __shared__ int sbase;
    if (tid == 0) sbase = 0;
    __syncthreads();
    for (int c = 0; c < T_TOK; c += 256) {
        int tok = c + tid;
        int pk = eidx[tok];
        int slot = -1;
        if ((pk & 255) == e) slot = tok * 2;
        else if ((pk >> 8) == e) slot = tok * 2 + 1;
        unsigned long long m = __ballot(slot >= 0);
        int prefix = __popcll(m & ((1ull << lane) - 1ull));
        if (lane == 0) wsum[wv] = __popcll(m);
        __syncthreads();
        if (tid == 0) {
            int s = sbase;
#pragma unroll
            for (int i = 0; i < 4; ++i) { wbase[i] = s; s += wsum[i]; }
            sbase = s;
        }
        __syncthreads();
        if (slot >= 0) list[e * T_TOK + wbase[wv] + prefix] = slot;
        __syncthreads();
    }
    if (tid == 0) counts[e] = sbase;
}

// ---------------- GEMM 1&3 fused: act = silu(X w1^T) * (X w3^T) ----------------
// BM=128, BN=64, BK=32, 3-ring, depth-2, counted vmcnt (R8/R12 schedule).
__global__ __launch_bounds__(256, 3) void gemm13_kernel(
    const unsigned short* __restrict__ xb,
    const unsigned short* __restrict__ w1b,
    const unsigned short* __restrict__ w3b,
    const int* __restrict__ list,
    const int* __restrict__ counts,
    unsigned short* __restrict__ act) {
    int orig = blockIdx.x;
    int wg = (orig & 7) * 768 + (orig >> 3);
    int tm = wg & 31;
    int tn = (wg >> 5) % 24;
    int e = wg / (32 * 24);

    int cnt = counts[e];
    if (tm * 128 >= cnt) return;
    const int* lst = list + e * T_TOK + tm * 128;
    int mrem = cnt - tm * 128;

    __shared__ unsigned short sA[3][128 * 32];   // 24 KB
    __shared__ unsigned short sB1[3][64 * 32];   // 12 KB
    __shared__ unsigned short sB3[3][64 * 32];   // 12 KB

    int tid = threadIdx.x;
    int lane = tid & 63;
    int wid = tid >> 6;

    int r0 = tid >> 2;
    int r1 = r0 + 64;
    int c8 = ((tid & 3) ^ ((r0 >> 1) & 3)) * 8;   // bank-correct pre-swizzle
    int tok0 = lst[(r0 < mrem) ? r0 : 0] >> 1;
    int tok1 = lst[(r1 < mrem) ? r1 : 0] >> 1;
    const unsigned short* gA0 = xb + (size_t)tok0 * H_DIM + c8;
    const unsigned short* gA1 = xb + (size_t)tok1 * H_DIM + c8;
    const unsigned short* gB1 = w1b + ((size_t)e * F_DIM + tn * 64 + r0) * H_DIM + c8;
    const unsigned short* gB3 = w3b + ((size_t)e * F_DIM + tn * 64 + r0) * H_DIM + c8;

    auto stage = [&](int b, int kt) {
        gload16(gA0 + kt, &sA[b][wid * 512]);
        gload16(gA1 + kt, &sA[b][2048 + wid * 512]);
        gload16(gB1 + kt, &sB1[b][wid * 512]);
        gload16(gB3 + kt, &sB3[b][wid * 512]);
    };

    int wr = (wid >> 1) * 64;
    int wc = (wid & 1) * 32;
    int fr = lane & 15;
    int kb = ((lane >> 4) ^ ((lane >> 1) & 3)) * 8;  // matching read XOR

    f32x4 accG[4][2] = {};
    f32x4 accU[4][2] = {};

    const int NT = H_DIM / 32;   // 24
    stage(0, 0);
    stage(1, 32);
    int cur = 0;
    for (int t = 0; t < NT; ++t) {
        if (t + 2 < NT) {
            int nb = cur + 2; if (nb >= 3) nb -= 3;
            stage(nb, (t + 2) * 32);
            VMCNT(8);
        } else if (t + 1 < NT) {
            VMCNT(4);
        } else {
            VMCNT(0);
        }
        __builtin_amdgcn_s_barrier();
        CFENCE();

        bf16x8 a[4], b1[2], b3[2];
#pragma unroll
        for (int mi = 0; mi < 4; ++mi)
            a[mi] = *reinterpret_cast<const bf16x8*>(&sA[cur][(wr + mi * 16 + fr) * 32 + kb]);
#pragma unroll
        for (int ni = 0; ni < 2; ++ni) {
            b1[ni] = *reinterpret_cast<const bf16x8*>(&sB1[cur][(wc + ni * 16 + fr) * 32 + kb]);
            b3[ni] = *reinterpret_cast<const bf16x8*>(&sB3[cur][(wc + ni * 16 + fr) * 32 + kb]);
        }
#pragma unroll
        for (int mi = 0; mi < 4; ++mi)
#pragma unroll
            for (int ni = 0; ni < 2; ++ni) {
                accG[mi][ni] = __builtin_amdgcn_mfma_f32_16x16x32_bf16(a[mi], b1[ni], accG[mi][ni], 0, 0, 0);
                accU[mi][ni] = __builtin_amdgcn_mfma_f32_16x16x32_bf16(a[mi], b3[ni], accU[mi][ni], 0, 0, 0);
            }
        CFENCE();
        __builtin_amdgcn_s_barrier();
        cur = (cur + 1 < 3) ? cur + 1 : 0;
    }

    int rg = (lane >> 4) * 4;
    int ci = lane & 15;
#pragma unroll
    for (int mi = 0; mi < 4; ++mi) {
#pragma unroll
        for (int r = 0; r < 4; ++r) {
            int m = wr + mi * 16 + rg + r;
            if (m >= mrem) continue;
            int entry = lst[m];
            size_t rowOff = (size_t)entry * F_DIM + tn * 64;
#pragma unroll
            for (int ni = 0; ni < 2; ++ni) {
                float g = accG[mi][ni][r];
                float u = accU[mi][ni][r];
                float s = g / (1.f + __expf(-g));
                act[rowOff + wc + ni * 16 + ci] = f2bf(s * u);
            }
        }
    }
}

// ---------------- GEMM 2: ybuf(bf16) = (act w2^T) * route_weight ----------------
// BM=128, BN=128, BK=32, 3-ring, depth 2, counted vmcnt (R8/R12 schedule).
__global__ __launch_bounds__(256, 3) void gemm2_kernel(
    const unsigned short* __restrict__ act,
    const unsigned short* __restrict__ w2b,
    const int* __restrict__ list,
    const int* __restrict__ counts,
    const float* __restrict__ weight,
    unsigned short* __restrict__ ybuf) {
    int orig = blockIdx.x;
    int wg = (orig & 7) * 192 + (orig >> 3);
    int tm = wg & 31;
    int tn = (wg >> 5) % 6;
    int e = wg / (32 * 6);

    int cnt = counts[e];
    if (tm * 128 >= cnt) return;
    const int* lst = list + e * T_TOK + tm * 128;
    int mrem = cnt - tm * 128;

    __shared__ unsigned short sA[3][128 * 32];   // 24 KB
    __shared__ unsigned short sB[3][128 * 32];   // 24 KB

    int tid = threadIdx.x;
    int lane = tid & 63;
    int wid = tid >> 6;

    int r0 = tid >> 2;
    int r1 = r0 + 64;
    int c8 = ((tid & 3) ^ ((r0 >> 1) & 3)) * 8;
    int row0 = lst[(r0 < mrem) ? r0 : 0];
    int row1 = lst[(r1 < mrem) ? r1 : 0];
    const unsigned short* gA0 = act + (size_t)row0 * F_DIM + c8;
    const unsigned short* gA1 = act + (size_t)row1 * F_DIM + c8;
    const unsigned short* gB0 = w2b + ((size_t)e * H_DIM + tn * 128 + r0) * F_DIM + c8;
    const unsigned short* gB1 = gB0 + (size_t)64 * F_DIM;

    auto stage = [&](int b, int kt) {
        gload16(gA0 + kt, &sA[b][wid * 512]);
        gload16(gA1 + kt, &sA[b][2048 + wid * 512]);
        gload16(gB0 + kt, &sB[b][wid * 512]);
        gload16(gB1 + kt, &sB[b][2048 + wid * 512]);
    };

    int wr = (wid >> 1) * 64;
    int wc = (wid & 1) * 64;
    int fr = lane & 15;
    int kb = ((lane >> 4) ^ ((lane >> 1) & 3)) * 8;

    f32x4 acc[4][4] = {};

    const int NT = F_DIM / 32;   // 48
    stage(0, 0);
    stage(1, 32);
    int cur = 0;
    for (int t = 0; t < NT; ++t) {
        if (t + 2 < NT) {
            int nb = cur + 2; if (nb >= 3) nb -= 3;
            stage(nb, (t + 2) * 32);
            VMCNT(8);
        } else if (t + 1 < NT) {
            VMCNT(4);
        } else {
            VMCNT(0);
        }
        __builtin_amdgcn_s_barrier();
        CFENCE();

        bf16x8 a[4], b[4];
#pragma unroll
        for (int mi = 0; mi < 4; ++mi)
            a[mi] = *reinterpret_cast<const bf16x8*>(&sA[cur][(wr + mi * 16 + fr) * 32 + kb]);
#pragma unroll
        for (int ni = 0; ni < 4; ++ni)
            b[ni] = *reinterpret_cast<const bf16x8*>(&sB[cur][(wc + ni * 16 + fr) * 32 + kb]);
#pragma unroll
        for (int mi = 0; mi < 4; ++mi)
#pragma unroll
            for (int ni = 0; ni < 4; ++ni)
                acc[mi][ni] = __builtin_amdgcn_mfma_f32_16x16x32_bf16(a[mi], b[ni], acc[mi][ni], 0, 0, 0);
        CFENCE();
        __builtin_amdgcn_s_barrier();
        cur = (cur + 1 < 3) ? cur + 1 : 0;
    }

    int rg = (lane >> 4) * 4;
    int ci = lane & 15;
#pragma unroll
    for (int mi = 0; mi < 4; ++mi) {
#pragma unroll
        for (int r = 0; r < 4; ++r) {
            int m = wr + mi * 16 + rg + r;
            if (m >= mrem) continue;
            int entry = lst[m];
            float wv = weight[entry];
            size_t rowOff = (size_t)entry * H_DIM + tn * 128;
#pragma unroll
            for (int ni = 0; ni < 4; ++ni)
                ybuf[rowOff + wc + ni * 16 + ci] = f2bf(acc[mi][ni][r] * wv);
        }
    }
}

// ---------------- combine: y[t] = ybuf[2t] + ybuf[2t+1]  (bf16 in, fp32 out) ----------------
__global__ __launch_bounds__(256) void combine_kernel(
    const unsigned short* __restrict__ ybuf, float* __restrict__ y) {
    int v = blockIdx.x * blockDim.x + threadIdx.x;   // over T*H/8
    if (v >= T_TOK * H_DIM / 8) return;
    int t = v / (H_DIM / 8);
    int hv = (v % (H_DIM / 8)) * 8;
    const ushort4* pa = reinterpret_cast<const ushort4*>(ybuf + (size_t)(2 * t) * H_DIM + hv);
    const ushort4* pb = reinterpret_cast<const ushort4*>(ybuf + (size_t)(2 * t + 1) * H_DIM + hv);
    float* yo = y + (size_t)t * H_DIM + hv;
#pragma unroll
    for (int h = 0; h < 2; ++h) {
        ushort4 a = pa[h];
        ushort4 b = pb[h];
        float4 r;
        r.x = bf2f(a.x) + bf2f(b.x);
        r.y = bf2f(a.y) + bf2f(b.y);
        r.z = bf2f(a.z) + bf2f(b.z);
        r.w = bf2f(a.w) + bf2f(b.w);
        *reinterpret_cast<float4*>(yo + h * 4) = r;
    }
}

extern "C" void kernel_launch(void* const* d_in, const int* in_sizes, int n_in,
                              void* d_out, int out_size, void* d_ws, size_t ws_size,
                              hipStream_t stream) {
    const float* x  = (const float*)d_in[0];
    const float* gw = (const float*)d_in[1];
    const float* w1 = (const float*)d_in[2];
    const float* w3 = (const float*)d_in[3];
    const float* w2 = (const float*)d_in[4];

    float* y = (float*)d_out;
    float* logits_out = y + (size_t)T_TOK * H_DIM;

    char* ws = (char*)d_ws;
    size_t off = 0;
    auto alloc = [&](size_t bytes) -> char* {
        char* p = ws + off;
        off += (bytes + 255) & ~(size_t)255;
        return p;
    };
    unsigned short* xb   = (unsigned short*)alloc((size_t)T_TOK * H_DIM * 2);
    unsigned short* w1b  = (unsigned short*)alloc((size_t)WELEM * 2);
    unsigned short* w3b  = (unsigned short*)alloc((size_t)WELEM * 2);
    unsigned short* w2b  = (unsigned short*)alloc((size_t)WELEM * 2);
    unsigned short* act  = (unsigned short*)alloc((size_t)T_TOK * 2 * F_DIM * 2);
    unsigned short* ybuf = (unsigned short*)alloc((size_t)T_TOK * 2 * H_DIM * 2);
    float* weight = (float*)alloc((size_t)T_TOK * 2 * 4);
    int* list     = (int*)alloc((size_t)E_NUM * T_TOK * 4);
    int* counts   = (int*)alloc((size_t)E_NUM * 4);
    int* eidx     = (int*)alloc((size_t)T_TOK * 4);

    prologue_kernel<<<3328, 256, 0, stream>>>(x, gw, w1, w3,
                                              logits_out, weight, eidx, xb,
                                              w1b, w3b);

    build_lists_kernel<<<2312, 256, 0, stream>>>(eidx, list, counts, w2, w2b);

    gemm13_kernel<<<6144, 256, 0, stream>>>(xb, w1b, w3b, list, counts, act);

    gemm2_kernel<<<1536, 256, 0, stream>>>(act, w2b, list, counts, weight, ybuf);

    combine_kernel<<<(T_TOK * H_DIM / 8 + 255) / 256, 256, 0, stream>>>(ybuf, y);
}